// Round 1
// baseline (41.579 us; speedup 1.0000x reference)
//
#include <hip/hip_runtime.h>

// NEAT-style sparse MLP forward.
// LAYER_SIZES = [256, 512, 512, 512, 512, 64], FAN_IN = 32, BATCH = 2048.
// Edge list is layer-ordered; each dst node owns 32 consecutive edges.
// src for layer l is entirely within layer l-1 -> ping-pong LDS buffers.

constexpr int TB    = 8;            // batch rows per block
constexpr int BLOCK = 512;          // threads per block (8 waves)
constexpr int NGRP  = BLOCK / TB;   // 64 node-groups per block

__global__ __launch_bounds__(BLOCK) void neat_fwd(
    const float* __restrict__ x,
    const float* __restrict__ w,
    const int*   __restrict__ src,
    float*       __restrict__ out,
    int batch)
{
    __shared__ float bufA[512 * TB];   // 16 KB
    __shared__ float bufB[512 * TB];   // 16 KB

    const int tid    = threadIdx.x;
    const int b      = tid & (TB - 1);     // batch lane within tile
    const int grp    = tid >> 3;           // node group (TB == 8)
    const int batch0 = blockIdx.x * TB;

    // Stage input layer (256 nodes x TB rows), coalesced on global reads.
    for (int i = tid; i < 256 * TB; i += BLOCK) {
        const int bb   = i >> 8;      // 0..TB-1
        const int node = i & 255;
        bufA[node * TB + bb] = x[(batch0 + bb) * 256 + node];
    }
    __syncthreads();

    float* prev = bufA;
    float* cur  = bufB;

    int e0      = 0;   // edge offset of current layer
    int offPrev = 0;   // global node-id offset of previous layer

#pragma unroll
    for (int l = 1; l <= 5; ++l) {
        const int N   = (l == 5) ? 64 : 512;   // nodes in this layer
        const int npg = N / NGRP;              // nodes per group: 8 or 1

        for (int ni = 0; ni < npg; ++ni) {
            const int node = grp * npg + ni;
            const int e    = e0 + node * 32;

            // 4-way split accumulators to break the FMA dependency chain.
            float s0 = 0.0f, s1 = 0.0f, s2 = 0.0f, s3 = 0.0f;
#pragma unroll
            for (int j = 0; j < 32; j += 4) {
                const int sl0 = src[e + j + 0] - offPrev;
                const int sl1 = src[e + j + 1] - offPrev;
                const int sl2 = src[e + j + 2] - offPrev;
                const int sl3 = src[e + j + 3] - offPrev;
                s0 = fmaf(prev[sl0 * TB + b], w[e + j + 0], s0);
                s1 = fmaf(prev[sl1 * TB + b], w[e + j + 1], s1);
                s2 = fmaf(prev[sl2 * TB + b], w[e + j + 2], s2);
                s3 = fmaf(prev[sl3 * TB + b], w[e + j + 3], s3);
            }
            const float s = (s0 + s1) + (s2 + s3);
            // sigmoid
            cur[node * TB + b] = __fdividef(1.0f, 1.0f + __expf(-s));
        }

        e0      += N * 32;
        offPrev += (l == 1) ? 256 : 512;   // OFFSETS[l] - OFFSETS[l-1]
        __syncthreads();
        float* t = prev; prev = cur; cur = t;
    }

    // prev now holds the final layer (64 nodes x TB rows); coalesced store.
    for (int i = tid; i < 64 * TB; i += BLOCK) {
        const int bb   = i >> 6;   // 0..TB-1
        const int node = i & 63;
        out[(batch0 + bb) * 64 + node] = prev[node * TB + bb];
    }
}

extern "C" void kernel_launch(void* const* d_in, const int* in_sizes, int n_in,
                              void* d_out, int out_size, void* d_ws, size_t ws_size,
                              hipStream_t stream)
{
    const float* x   = (const float*)d_in[0];
    const float* w   = (const float*)d_in[1];
    const int*   src = (const int*)d_in[2];
    // d_in[3] (dst) is fully implied by the layer structure; unused.
    float* out = (float*)d_out;

    const int batch = in_sizes[0] / 256;       // 2048
    const int grid  = batch / TB;              // 256 blocks

    neat_fwd<<<grid, BLOCK, 0, stream>>>(x, w, src, out, batch);
}

// Round 2
// 26.024 us; speedup vs baseline: 1.5977x; 1.5977x over previous
//
#include <hip/hip_runtime.h>

// NEAT sparse MLP fwd. LAYER_SIZES = [256,512,512,512,512,64], FAN_IN=32, BATCH=2048.
// OFFSETS = [0,256,768,1280,1792,2304,2368]; E_tot = 67584.
//
// R2 design: TB=4 batch rows per block (grid=512 -> 2 blocks/CU), thread owns the
// whole batch-quad (float4 acc, ds_read_b128 activation gathers), thread==node for
// 512-node layers. Edges pre-packed into d_ws as (int4 byte-offsets, float4 weights)
// chunk-transposed per 64-node wave group so edge loads are contiguous per wave.

constexpr int TB    = 4;
constexpr int BLOCK = 512;
constexpr int E_TOT = 67584;

__global__ void pack_edges(const int* __restrict__ src, const float* __restrict__ w,
                           int* __restrict__ sp, float* __restrict__ wp)
{
    const int o = blockIdx.x * blockDim.x + threadIdx.x;
    if (o >= E_TOT) return;
    int e0, offPrev;
    if      (o < 16384) { e0 = 0;     offPrev = 0;    }
    else if (o < 32768) { e0 = 16384; offPrev = 256;  }
    else if (o < 49152) { e0 = 32768; offPrev = 768;  }
    else if (o < 65536) { e0 = 49152; offPrev = 1280; }
    else                { e0 = 65536; offPrev = 1792; }
    const int ol = o - e0;
    // ol = ((g*8 + c)*64 + i)*4 + q   ->   eid = e0 + (g*64+i)*32 + c*4 + q
    const int q  = ol & 3;
    const int t  = ol >> 2;
    const int i  = t & 63;
    const int gc = t >> 6;
    const int c  = gc & 7;
    const int g  = gc >> 3;
    const int eid = e0 + (g * 64 + i) * 32 + c * 4 + q;
    sp[o] = (src[eid] - offPrev) << 4;   // byte offset into [node][TB] fp32 LDS buffer
    wp[o] = w[eid];
}

template<bool PACKED>
__global__ __launch_bounds__(BLOCK) void neat_fwd(
    const float* __restrict__ x,
    const float* __restrict__ w,
    const int*   __restrict__ src,
    const int*   __restrict__ sp,
    const float* __restrict__ wp,
    float*       __restrict__ out)
{
    __shared__ __align__(16) float bufA[512 * TB];   // 8 KB
    __shared__ __align__(16) float bufB[512 * TB];   // 8 KB

    const int tid    = threadIdx.x;
    const int batch0 = blockIdx.x * TB;

    // Stage input layer: 256 nodes x 4 rows. 256 threads read one float4 each
    // (coalesced); transpose into [node][q] in LDS.
    if (tid < 256) {
        const int q  = tid >> 6;          // 0..3
        const int n4 = (tid & 63) * 4;    // node base
        const float4 v = *(const float4*)(x + (size_t)(batch0 + q) * 256 + n4);
        bufA[(n4 + 0) * TB + q] = v.x;
        bufA[(n4 + 1) * TB + q] = v.y;
        bufA[(n4 + 2) * TB + q] = v.z;
        bufA[(n4 + 3) * TB + q] = v.w;
    }
    __syncthreads();

    float* prev = bufA;
    float* cur  = bufB;

#define LAYER(N, E0, OFFPREV)                                                   \
    do {                                                                        \
        const int node = tid;                                                   \
        if (node < (N)) {                                                       \
            const char* pv = (const char*)prev;                                 \
            float4 accA = {0.f, 0.f, 0.f, 0.f};                                 \
            float4 accB = {0.f, 0.f, 0.f, 0.f};                                 \
            if (PACKED) {                                                       \
                const int g = node >> 6, i = node & 63;                         \
                const int4*   s4 = (const int4*)(sp + (E0)) + g * 512 + i;      \
                const float4* w4 = (const float4*)(wp + (E0)) + g * 512 + i;    \
                _Pragma("unroll")                                               \
                for (int c = 0; c < 8; ++c) {                                   \
                    const int4   s  = s4[c * 64];                               \
                    const float4 ww = w4[c * 64];                               \
                    const float4 a0 = *(const float4*)(pv + s.x);               \
                    const float4 a1 = *(const float4*)(pv + s.y);               \
                    const float4 a2 = *(const float4*)(pv + s.z);               \
                    const float4 a3 = *(const float4*)(pv + s.w);               \
                    accA.x = fmaf(a0.x, ww.x, accA.x); accA.y = fmaf(a0.y, ww.x, accA.y); \
                    accA.z = fmaf(a0.z, ww.x, accA.z); accA.w = fmaf(a0.w, ww.x, accA.w); \
                    accB.x = fmaf(a1.x, ww.y, accB.x); accB.y = fmaf(a1.y, ww.y, accB.y); \
                    accB.z = fmaf(a1.z, ww.y, accB.z); accB.w = fmaf(a1.w, ww.y, accB.w); \
                    accA.x = fmaf(a2.x, ww.z, accA.x); accA.y = fmaf(a2.y, ww.z, accA.y); \
                    accA.z = fmaf(a2.z, ww.z, accA.z); accA.w = fmaf(a2.w, ww.z, accA.w); \
                    accB.x = fmaf(a3.x, ww.w, accB.x); accB.y = fmaf(a3.y, ww.w, accB.y); \
                    accB.z = fmaf(a3.z, ww.w, accB.z); accB.w = fmaf(a3.w, ww.w, accB.w); \
                }                                                               \
            } else {                                                            \
                const int ebase = (E0) + node * 32;                             \
                _Pragma("unroll")                                               \
                for (int c = 0; c < 8; ++c) {                                   \
                    const int4   s  = *(const int4*)(src + ebase + c * 4);      \
                    const float4 ww = *(const float4*)(w + ebase + c * 4);      \
                    const float4 a0 = *(const float4*)(pv + ((s.x - (OFFPREV)) << 4)); \
                    const float4 a1 = *(const float4*)(pv + ((s.y - (OFFPREV)) << 4)); \
                    const float4 a2 = *(const float4*)(pv + ((s.z - (OFFPREV)) << 4)); \
                    const float4 a3 = *(const float4*)(pv + ((s.w - (OFFPREV)) << 4)); \
                    accA.x = fmaf(a0.x, ww.x, accA.x); accA.y = fmaf(a0.y, ww.x, accA.y); \
                    accA.z = fmaf(a0.z, ww.x, accA.z); accA.w = fmaf(a0.w, ww.x, accA.w); \
                    accB.x = fmaf(a1.x, ww.y, accB.x); accB.y = fmaf(a1.y, ww.y, accB.y); \
                    accB.z = fmaf(a1.z, ww.y, accB.z); accB.w = fmaf(a1.w, ww.y, accB.w); \
                    accA.x = fmaf(a2.x, ww.z, accA.x); accA.y = fmaf(a2.y, ww.z, accA.y); \
                    accA.z = fmaf(a2.z, ww.z, accA.z); accA.w = fmaf(a2.w, ww.z, accA.w); \
                    accB.x = fmaf(a3.x, ww.w, accB.x); accB.y = fmaf(a3.y, ww.w, accB.y); \
                    accB.z = fmaf(a3.z, ww.w, accB.z); accB.w = fmaf(a3.w, ww.w, accB.w); \
                }                                                               \
            }                                                                   \
            float4 r;                                                           \
            r.x = __fdividef(1.f, 1.f + __expf(-(accA.x + accB.x)));            \
            r.y = __fdividef(1.f, 1.f + __expf(-(accA.y + accB.y)));            \
            r.z = __fdividef(1.f, 1.f + __expf(-(accA.z + accB.z)));            \
            r.w = __fdividef(1.f, 1.f + __expf(-(accA.w + accB.w)));            \
            *(float4*)(cur + node * TB) = r;                                    \
        }                                                                       \
        __syncthreads();                                                        \
        float* tmp = prev; prev = cur; cur = tmp;                               \
    } while (0)

    LAYER(512, 0,     0);
    LAYER(512, 16384, 256);
    LAYER(512, 32768, 768);
    LAYER(512, 49152, 1280);
    LAYER(64,  65536, 1792);
#undef LAYER

    // prev holds layer-5 output: 64 nodes x 4 rows = 256 floats.
    if (tid < 64 * TB) {
        const int q = tid >> 6;
        const int n = tid & 63;
        out[(size_t)(batch0 + q) * 64 + n] = prev[n * TB + q];
    }
}

extern "C" void kernel_launch(void* const* d_in, const int* in_sizes, int n_in,
                              void* d_out, int out_size, void* d_ws, size_t ws_size,
                              hipStream_t stream)
{
    const float* x   = (const float*)d_in[0];
    const float* w   = (const float*)d_in[1];
    const int*   src = (const int*)d_in[2];
    float* out = (float*)d_out;

    const int batch = in_sizes[0] / 256;   // 2048
    const int grid  = batch / TB;          // 512 blocks

    const size_t need = (size_t)E_TOT * 8;
    int*   sp = (int*)d_ws;
    float* wp = (float*)((char*)d_ws + (size_t)E_TOT * 4);

    if (ws_size >= need) {
        pack_edges<<<(E_TOT + 255) / 256, 256, 0, stream>>>(src, w, sp, wp);
        neat_fwd<true><<<grid, BLOCK, 0, stream>>>(x, w, src, sp, wp, out);
    } else {
        neat_fwd<false><<<grid, BLOCK, 0, stream>>>(x, w, src, sp, wp, out);
    }
}

// Round 3
// 23.373 us; speedup vs baseline: 1.7789x; 1.1134x over previous
//
#include <hip/hip_runtime.h>
#include <hip/hip_fp16.h>

// NEAT sparse MLP fwd. LAYER_SIZES=[256,512,512,512,512,64], FAN_IN=32, BATCH=2048.
// OFFSETS=[0,256,768,1280,1792,2304,2368]; E_TOT=67584.
//
// R3: f16 activations in LDS (halves gather bytes -> ds_read_b64 per edge),
// 4B packed edge records (byte_off:16 | w_f16:16) halving the L2 edge stream,
// f32 accumulators, layer-5 spread over all 512 threads. TB=4, grid=512
// (2 blocks/CU, 16 waves/CU).

typedef _Float16 half4_t __attribute__((ext_vector_type(4)));

constexpr int TB    = 4;
constexpr int BLOCK = 512;
constexpr int E_TOT = 67584;

__global__ void pack_edges(const int* __restrict__ src, const float* __restrict__ w,
                           unsigned* __restrict__ rec)
{
    const int o = blockIdx.x * 256 + threadIdx.x;
    if (o >= E_TOT) return;
    int e0, offPrev;
    if      (o < 16384) { e0 = 0;     offPrev = 0;    }
    else if (o < 32768) { e0 = 16384; offPrev = 256;  }
    else if (o < 49152) { e0 = 32768; offPrev = 768;  }
    else if (o < 65536) { e0 = 49152; offPrev = 1280; }
    else                { e0 = 65536; offPrev = 1792; }
    const int ol = o - e0;
    int eid;
    if (e0 == 65536) {
        // layer 5: record int4 r = tid; r = c*64+n ; eid = n*32 + c*4 + q
        const int q = ol & 3, r = ol >> 2;
        const int c = r >> 6, n = r & 63;
        eid = e0 + n * 32 + c * 4 + q;
    } else {
        // 512-layers: word idx = ((g*8+c)*64 + i)*4 + q ; eid = (g*64+i)*32 + c*4 + q
        const int q = ol & 3, t = ol >> 2;
        const int i = t & 63, c = (t >> 6) & 7, g = t >> 9;
        eid = e0 + (g * 64 + i) * 32 + c * 4 + q;
    }
    const unsigned off = (unsigned)(src[eid] - offPrev) * (TB * 2);  // byte off into f16 [node][TB]
    const unsigned hw  = (unsigned)__half_as_ushort(__float2half(w[eid]));
    rec[o] = off | (hw << 16);
}

__device__ __forceinline__ float sigmoidf(float s)
{
    return __fdividef(1.0f, 1.0f + __expf(-s));
}

template<bool PACKED>
__global__ __launch_bounds__(BLOCK) void neat_fwd(
    const float* __restrict__ x,
    const float* __restrict__ w,
    const int*   __restrict__ src,
    const int4*  __restrict__ rp,      // packed records as int4 (4 edges)
    float*       __restrict__ out)
{
    __shared__ __align__(16) _Float16 bufA[512 * TB];   // 4 KB
    __shared__ __align__(16) _Float16 bufB[512 * TB];   // 4 KB
    __shared__ float l5p[512 * 5];                      // 10 KB, stride-5 pad

    const int tid    = threadIdx.x;
    const int batch0 = blockIdx.x * TB;

    // Stage input layer as f16: 256 nodes x 4 rows.
    if (tid < 256) {
        const int r  = tid >> 6;
        const int c4 = (tid & 63) * 4;
        const float4 v = *(const float4*)(x + (size_t)(batch0 + r) * 256 + c4);
        bufA[(c4 + 0) * TB + r] = (_Float16)v.x;
        bufA[(c4 + 1) * TB + r] = (_Float16)v.y;
        bufA[(c4 + 2) * TB + r] = (_Float16)v.z;
        bufA[(c4 + 3) * TB + r] = (_Float16)v.w;
    }
    __syncthreads();

    _Float16* prev = bufA;
    _Float16* cur  = bufB;

    const int base = (tid >> 6) * 512 + (tid & 63);   // int4 index within a 512-layer

#define EDGE(RR, ACC)                                                          \
    do {                                                                       \
        const unsigned rr = (unsigned)(RR);                                    \
        const float wf = __half2float(__ushort_as_half((unsigned short)(rr >> 16))); \
        const half4_t a = *(const half4_t*)(pv + (rr & 0xffffu));              \
        ACC.x = fmaf((float)a[0], wf, ACC.x);                                  \
        ACC.y = fmaf((float)a[1], wf, ACC.y);                                  \
        ACC.z = fmaf((float)a[2], wf, ACC.z);                                  \
        ACC.w = fmaf((float)a[3], wf, ACC.w);                                  \
    } while (0)

#define EDGE_RAW(SRCID, WF, ACC)                                               \
    do {                                                                       \
        const float wf = (WF);                                                 \
        const half4_t a = *(const half4_t*)(pv + (unsigned)((SRCID) - offPrev) * (TB * 2)); \
        ACC.x = fmaf((float)a[0], wf, ACC.x);                                  \
        ACC.y = fmaf((float)a[1], wf, ACC.y);                                  \
        ACC.z = fmaf((float)a[2], wf, ACC.z);                                  \
        ACC.w = fmaf((float)a[3], wf, ACC.w);                                  \
    } while (0)

    // Layers 1..4 (512 nodes each): thread == node.
#pragma unroll
    for (int l = 0; l < 4; ++l) {
        const char* pv = (const char*)prev;
        float4 accA = {0.f, 0.f, 0.f, 0.f};
        float4 accB = {0.f, 0.f, 0.f, 0.f};
        if (PACKED) {
            const int4* rl = rp + l * 4096;
#pragma unroll
            for (int c = 0; c < 8; ++c) {
                const int4 r4 = rl[base + c * 64];
                EDGE(r4.x, accA);
                EDGE(r4.y, accB);
                EDGE(r4.z, accA);
                EDGE(r4.w, accB);
            }
        } else {
            const int e0 = l * 16384;
            const int offPrev = (l == 0) ? 0 : (256 + (l - 1) * 512);
            const int ebase = e0 + tid * 32;
#pragma unroll
            for (int c = 0; c < 8; ++c) {
                const int4   s4 = *(const int4*)(src + ebase + c * 4);
                const float4 w4 = *(const float4*)(w + ebase + c * 4);
                EDGE_RAW(s4.x, w4.x, accA);
                EDGE_RAW(s4.y, w4.y, accB);
                EDGE_RAW(s4.z, w4.z, accA);
                EDGE_RAW(s4.w, w4.w, accB);
            }
        }
        half4_t r;
        r[0] = (_Float16)sigmoidf(accA.x + accB.x);
        r[1] = (_Float16)sigmoidf(accA.y + accB.y);
        r[2] = (_Float16)sigmoidf(accA.z + accB.z);
        r[3] = (_Float16)sigmoidf(accA.w + accB.w);
        *(half4_t*)(cur + tid * TB) = r;
        __syncthreads();
        _Float16* t = prev; prev = cur; cur = t;
    }

    // Layer 5: 64 nodes x 32 edges = 512 int4 records; thread tid handles
    // node n=tid&63, chunk c=tid>>6 (4 edges). Partial sums -> padded LDS.
    {
        const char* pv = (const char*)prev;
        float4 accA = {0.f, 0.f, 0.f, 0.f};
        float4 accB = {0.f, 0.f, 0.f, 0.f};
        if (PACKED) {
            const int4 r4 = rp[16384 + tid];
            EDGE(r4.x, accA);
            EDGE(r4.y, accB);
            EDGE(r4.z, accA);
            EDGE(r4.w, accB);
        } else {
            const int n = tid & 63, c = tid >> 6;
            const int offPrev = 1792;
            const int eb = 65536 + n * 32 + c * 4;
            const int4   s4 = *(const int4*)(src + eb);
            const float4 w4 = *(const float4*)(w + eb);
            EDGE_RAW(s4.x, w4.x, accA);
            EDGE_RAW(s4.y, w4.y, accB);
            EDGE_RAW(s4.z, w4.z, accA);
            EDGE_RAW(s4.w, w4.w, accB);
        }
        float* dst = l5p + tid * 5;
        dst[0] = accA.x + accB.x;
        dst[1] = accA.y + accB.y;
        dst[2] = accA.z + accB.z;
        dst[3] = accA.w + accB.w;
    }
    __syncthreads();

    // Reduce 8 chunk-partials per (node, batch) and store. 256 active threads.
    if (tid < 256) {
        const int n = tid & 63;
        const int b = tid >> 6;
        float s = 0.f;
#pragma unroll
        for (int c = 0; c < 8; ++c)
            s += l5p[(c * 64 + n) * 5 + b];
        out[(size_t)(batch0 + b) * 64 + n] = sigmoidf(s);
    }
#undef EDGE
#undef EDGE_RAW
}

extern "C" void kernel_launch(void* const* d_in, const int* in_sizes, int n_in,
                              void* d_out, int out_size, void* d_ws, size_t ws_size,
                              hipStream_t stream)
{
    const float* x   = (const float*)d_in[0];
    const float* w   = (const float*)d_in[1];
    const int*   src = (const int*)d_in[2];
    float* out = (float*)d_out;

    const int batch = in_sizes[0] / 256;   // 2048
    const int grid  = batch / TB;          // 512

    unsigned* rec = (unsigned*)d_ws;

    if (ws_size >= (size_t)E_TOT * 4) {
        pack_edges<<<(E_TOT + 255) / 256, 256, 0, stream>>>(src, w, rec);
        neat_fwd<true><<<grid, BLOCK, 0, stream>>>(x, w, src, (const int4*)rec, out);
    } else {
        neat_fwd<false><<<grid, BLOCK, 0, stream>>>(x, w, src, (const int4*)rec, out);
    }
}

// Round 4
// 21.307 us; speedup vs baseline: 1.9514x; 1.0970x over previous
//
#include <hip/hip_runtime.h>
#include <hip/hip_fp16.h>

// NEAT sparse MLP fwd. LAYER_SIZES=[256,512,512,512,512,64], FAN_IN=32, BATCH=2048.
// OFFSETS=[0,256,768,1280,1792,2304,2368]; E_TOT=67584.
//
// R4: TB=8 batch rows per thread, f16 activations in LDS laid out [node][8]
// (16 B/node) -> ONE ds_read_b128 per edge feeds 8 f32 FMAs. Packed 4 B edge
// records (byte_off:16 | w_f16:16), chunk-transposed per 64-node wave group.
// grid = 256 blocks (1 block/CU, 8 waves), f32 accumulators, layer-5 spread
// over all 512 threads with padded partial reduce.

typedef _Float16 half8_t  __attribute__((ext_vector_type(8)));
typedef float    float8_t __attribute__((ext_vector_type(8)));

constexpr int TB    = 8;
constexpr int BLOCK = 512;
constexpr int E_TOT = 67584;

__global__ void pack_edges(const int* __restrict__ src, const float* __restrict__ w,
                           unsigned* __restrict__ rec)
{
    const int o = blockIdx.x * 256 + threadIdx.x;
    if (o >= E_TOT) return;
    int e0, offPrev;
    if      (o < 16384) { e0 = 0;     offPrev = 0;    }
    else if (o < 32768) { e0 = 16384; offPrev = 256;  }
    else if (o < 49152) { e0 = 32768; offPrev = 768;  }
    else if (o < 65536) { e0 = 49152; offPrev = 1280; }
    else                { e0 = 65536; offPrev = 1792; }
    const int ol = o - e0;
    int eid;
    if (e0 == 65536) {
        // layer 5: int4 record index r = tid = c*64+n ; eid = n*32 + c*4 + q
        const int q = ol & 3, r = ol >> 2;
        const int c = r >> 6, n = r & 63;
        eid = e0 + n * 32 + c * 4 + q;
    } else {
        // 512-layers: word idx = ((g*8+c)*64 + i)*4 + q ; eid = (g*64+i)*32 + c*4 + q
        const int q = ol & 3, t = ol >> 2;
        const int i = t & 63, c = (t >> 6) & 7, g = t >> 9;
        eid = e0 + (g * 64 + i) * 32 + c * 4 + q;
    }
    const unsigned off = (unsigned)(src[eid] - offPrev) * (TB * 2);  // byte off, [node][8] f16
    const unsigned hw  = (unsigned)__half_as_ushort(__float2half(w[eid]));
    rec[o] = off | (hw << 16);
}

__device__ __forceinline__ float sigmoidf(float s)
{
    return __fdividef(1.0f, 1.0f + __expf(-s));
}

template<bool PACKED>
__global__ __launch_bounds__(BLOCK) void neat_fwd(
    const float* __restrict__ x,
    const float* __restrict__ w,
    const int*   __restrict__ src,
    const int4*  __restrict__ rp,      // packed records as int4 (4 edges)
    float*       __restrict__ out)
{
    __shared__ __align__(16) _Float16 bufA[512 * TB];   // 8 KB
    __shared__ __align__(16) _Float16 bufB[512 * TB];   // 8 KB
    __shared__ float l5p[512 * 9];                      // 18 KB, stride-9 pad

    const int tid    = threadIdx.x;
    const int batch0 = blockIdx.x * TB;

    // Stage input layer as f16 [node][8]: 256 nodes x 8 rows. Thread reads one
    // coalesced float4 of row r, scatters 4 nodes' entries.
    {
        const int r  = tid >> 6;          // 0..7
        const int c4 = (tid & 63) * 4;    // node base
        const float4 v = *(const float4*)(x + (size_t)(batch0 + r) * 256 + c4);
        bufA[(c4 + 0) * TB + r] = (_Float16)v.x;
        bufA[(c4 + 1) * TB + r] = (_Float16)v.y;
        bufA[(c4 + 2) * TB + r] = (_Float16)v.z;
        bufA[(c4 + 3) * TB + r] = (_Float16)v.w;
    }
    __syncthreads();

    _Float16* prev = bufA;
    _Float16* cur  = bufB;

    const int base = (tid >> 6) * 512 + (tid & 63);   // int4 index within a 512-layer

#define EDGE(RR, ACC)                                                          \
    do {                                                                       \
        const unsigned rr = (unsigned)(RR);                                    \
        const float wf = __half2float(__ushort_as_half((unsigned short)(rr >> 16))); \
        const half8_t a = *(const half8_t*)(pv + (rr & 0xffffu));              \
        _Pragma("unroll")                                                      \
        for (int k = 0; k < 8; ++k)                                            \
            ACC[k] = fmaf((float)a[k], wf, ACC[k]);                            \
    } while (0)

#define EDGE_RAW(SRCID, WF, ACC)                                               \
    do {                                                                       \
        const float wf = (WF);                                                 \
        const half8_t a = *(const half8_t*)(pv + (unsigned)((SRCID) - offPrev) * (TB * 2)); \
        _Pragma("unroll")                                                      \
        for (int k = 0; k < 8; ++k)                                            \
            ACC[k] = fmaf((float)a[k], wf, ACC[k]);                            \
    } while (0)

    // Layers 1..4 (512 nodes each): thread == node.
#pragma unroll
    for (int l = 0; l < 4; ++l) {
        const char* pv = (const char*)prev;
        float8_t acc = {0.f, 0.f, 0.f, 0.f, 0.f, 0.f, 0.f, 0.f};
        if (PACKED) {
            const int4* rl = rp + l * 4096;
#pragma unroll
            for (int c = 0; c < 8; ++c) {
                const int4 r4 = rl[base + c * 64];
                EDGE(r4.x, acc);
                EDGE(r4.y, acc);
                EDGE(r4.z, acc);
                EDGE(r4.w, acc);
            }
        } else {
            const int e0 = l * 16384;
            const int offPrev = (l == 0) ? 0 : (256 + (l - 1) * 512);
            const int ebase = e0 + tid * 32;
#pragma unroll
            for (int c = 0; c < 8; ++c) {
                const int4   s4 = *(const int4*)(src + ebase + c * 4);
                const float4 w4 = *(const float4*)(w + ebase + c * 4);
                EDGE_RAW(s4.x, w4.x, acc);
                EDGE_RAW(s4.y, w4.y, acc);
                EDGE_RAW(s4.z, w4.z, acc);
                EDGE_RAW(s4.w, w4.w, acc);
            }
        }
        half8_t r;
#pragma unroll
        for (int k = 0; k < 8; ++k)
            r[k] = (_Float16)sigmoidf(acc[k]);
        *(half8_t*)(cur + tid * TB) = r;
        __syncthreads();
        _Float16* t = prev; prev = cur; cur = t;
    }

    // Layer 5: 64 nodes x 32 edges; thread tid = c*64+n handles 4 edges of
    // node n (chunk c). Partial float8 -> padded LDS, then reduce.
    {
        const char* pv = (const char*)prev;
        float8_t acc = {0.f, 0.f, 0.f, 0.f, 0.f, 0.f, 0.f, 0.f};
        if (PACKED) {
            const int4 r4 = rp[16384 + tid];
            EDGE(r4.x, acc);
            EDGE(r4.y, acc);
            EDGE(r4.z, acc);
            EDGE(r4.w, acc);
        } else {
            const int n = tid & 63, c = tid >> 6;
            const int offPrev = 1792;
            const int eb = 65536 + n * 32 + c * 4;
            const int4   s4 = *(const int4*)(src + eb);
            const float4 w4 = *(const float4*)(w + eb);
            EDGE_RAW(s4.x, w4.x, acc);
            EDGE_RAW(s4.y, w4.y, acc);
            EDGE_RAW(s4.z, w4.z, acc);
            EDGE_RAW(s4.w, w4.w, acc);
        }
        float* dst = l5p + tid * 9;
#pragma unroll
        for (int k = 0; k < 8; ++k)
            dst[k] = acc[k];
    }
    __syncthreads();

    // Reduce 8 chunk-partials per (node, batch row) and store; 512 threads,
    // tid -> n = tid&63 (coalesced stores), b = tid>>6.
    {
        const int n = tid & 63;
        const int b = tid >> 6;
        float s = 0.f;
#pragma unroll
        for (int c = 0; c < 8; ++c)
            s += l5p[(c * 64 + n) * 9 + b];
        out[(size_t)(batch0 + b) * 64 + n] = sigmoidf(s);
    }
#undef EDGE
#undef EDGE_RAW
}

extern "C" void kernel_launch(void* const* d_in, const int* in_sizes, int n_in,
                              void* d_out, int out_size, void* d_ws, size_t ws_size,
                              hipStream_t stream)
{
    const float* x   = (const float*)d_in[0];
    const float* w   = (const float*)d_in[1];
    const int*   src = (const int*)d_in[2];
    float* out = (float*)d_out;

    const int batch = in_sizes[0] / 256;   // 2048
    const int grid  = batch / TB;          // 256

    unsigned* rec = (unsigned*)d_ws;

    if (ws_size >= (size_t)E_TOT * 4) {
        pack_edges<<<(E_TOT + 255) / 256, 256, 0, stream>>>(src, w, rec);
        neat_fwd<true><<<grid, BLOCK, 0, stream>>>(x, w, src, (const int4*)rec, out);
    } else {
        neat_fwd<false><<<grid, BLOCK, 0, stream>>>(x, w, src, (const int4*)rec, out);
    }
}